// Round 4
// baseline (1491.438 us; speedup 1.0000x reference)
//
#include <hip/hip_runtime.h>

// Problem constants
#define BB   2
#define HH   256
#define WW   256
#define HWSZ (HH * WW)        // 65536
#define CC   24
#define KSZ  7
#define KK   49               // 7*7
#define PADK 3
#define G    8                // channel groups
#define CPG  3                // channels per group
#define LSTR 24               // src halo row stride (22 padded to 24)

typedef __attribute__((ext_vector_type(8))) short short8;
typedef __attribute__((ext_vector_type(4))) float float4v;

// float -> bf16 bits (round-to-nearest-even) and back
__device__ __forceinline__ short f2bf(float x) {
  unsigned u = __builtin_bit_cast(unsigned, x);
  unsigned r = u + 0x7FFFu + ((u >> 16) & 1u);
  return (short)(r >> 16);
}
__device__ __forceinline__ float bf2f(short h) {
  unsigned u = ((unsigned)(unsigned short)h) << 16;
  return __builtin_bit_cast(float, u);
}

// ---------------------------------------------------------------------------
// Setup: split-bf16 W fragments in MFMA A-operand friendly layout.
// wsW[blk][row 16][k 40], blk = ((g*3+c)*4 + mt)*2 + s  (192 blocks x 640)
// row = m within M-tile, k = 0..27 real (27 conv wts + bias at k=27), rest 0.
// Row stride 40 halves (80 B): 16B-aligned b128 reads, 2-way banks (free).
// ---------------------------------------------------------------------------
__global__ __launch_bounds__(64) void k_wsetup(
    const float* __restrict__ w_kp, const float* __restrict__ b_kp,
    short* __restrict__ wsW) {
  int blk = blockIdx.x;
  int s = blk & 1, mt = (blk >> 1) & 3, cg = blk >> 3;   // cg = g*3+c
  for (int idx = threadIdx.x; idx < 640; idx += 64) {
    int row = idx / 40, k = idx % 40;
    int kk = mt * 16 + row;
    float v = 0.f;
    if (kk < KK && k < 28)
      v = (k < 27) ? w_kp[((size_t)cg * KK + kk) * 27 + k] : b_kp[cg * KK + kk];
    short hi = f2bf(v);
    short h = (s == 0) ? hi : f2bf(v - bf2f(hi));
    wsW[(size_t)blk * 640 + idx] = h;
  }
}

// ---------------------------------------------------------------------------
// One diffusion iteration, logit conv done with split-bf16 MFMA.
// Per block: 16x16 pixel tile, 3-channel group. Per (c): 4 M-tiles of taps
// (rows 0..48 real), N = 256 pixels as 16 col-tiles; wave wv owns pixel rows
// wv*4..wv*4+3 (N-tiles). C-layout: col(lane&15)=pixel-x, row(quad*4+i)=tap.
// epilogue per C value: e=exp(logit) (bias via k=27, patch=1), z+=e (FIRST),
// acc += e * lsrc[c][pixel+tapoffset]. Cross-quad reduce via shfl_xor 16/32.
// ---------------------------------------------------------------------------
template <bool FIRST, bool FINAL>
__global__ __launch_bounds__(256, 3) void k_diffuse_m(
    const float* __restrict__ depth, const float* __restrict__ src,
    const float* __restrict__ invZ, const float* __restrict__ tex,
    const float* __restrict__ w_dp, const float* __restrict__ b_dp,
    const short* __restrict__ wsW, float* __restrict__ dst,
    float* __restrict__ part, const float* __restrict__ w_td) {
  __shared__ float lsrc[CPG * 22 * LSTR];          // 6336 B
  __shared__ float lt[3 * 324];                    // 3888 B  (18x18 tex halo)
  __shared__ __align__(16) short lw[24 * 640];     // 30720 B (W frags)
  __shared__ float ldp[576];                       // 2304 B  (24x24 depth halo)
  __shared__ int loffs[64];                        // tap -> src-halo offset
  __shared__ int lltk[32];                         // k -> tex-halo offset

  int b = blockIdx.z / G, g = blockIdx.z % G, c0 = g * CPG;
  int x0 = blockIdx.x * 16, y0 = blockIdx.y * 16;
  int tid = threadIdx.x;
  int lane = tid & 63, wv = tid >> 6;
  int q = lane >> 4, col = lane & 15;

  // tables
  if (tid < 64) {
    int r = tid;
    loffs[r] = (r < KK) ? ((r / 7) - 3) * LSTR + ((r % 7) - 3) : 0;
  } else if (tid < 96) {
    int k = tid - 64, v;
    if (k < 27) v = (k / 9) * 324 + ((k % 9) / 3) * 18 + (k % 3);
    else if (k == 27) v = -1;       // bias slot: patch value 1.0
    else v = -2;                    // K padding: 0.0
    lltk[k] = v;
  }
  // stage W fragments for this group (L2-hot, coalesced)
  {
    const int4* s4 = (const int4*)(wsW + (size_t)g * 15360);
    int4* d4 = (int4*)lw;
    for (int i = tid; i < 1920; i += 256) d4[i] = s4[i];
  }
  // stage texture halo
  for (int idx = tid; idx < 972; idx += 256) {
    int ci = idx / 324, r = idx % 324;
    int iy = r / 18, ix = r % 18;
    int yy = y0 + iy - 1, xx = x0 + ix - 1;
    bool ok = (yy >= 0 && yy < HH && xx >= 0 && xx < WW);
    lt[idx] = ok ? tex[((size_t)b * 3 + ci) * HWSZ + yy * WW + xx] : 0.f;
  }
  if (FIRST) {
    // depth halo 24x24 at (y0-4, x0-4)
    for (int idx = tid; idx < 576; idx += 256) {
      int iy = idx / 24, ix = idx % 24;
      int yy = y0 + iy - 4, xx = x0 + ix - 4;
      bool ok = (yy >= 0 && yy < HH && xx >= 0 && xx < WW);
      ldp[idx] = ok ? depth[(size_t)b * HWSZ + yy * WW + xx] : 0.f;
    }
  }
  __syncthreads();

  // stage src halo (22x22 at (y0-3,x0-3)); FIRST fuses depth_latent conv,
  // later iters fold previous 1/Z into the (unnormalized) src.
  for (int idx = tid; idx < 484; idx += 256) {
    int iy = idx / 22, ix = idx % 22;
    int yy = y0 + iy - PADK, xx = x0 + ix - PADK;
    bool ok = (yy >= 0 && yy < HH && xx >= 0 && xx < WW);
    if (FIRST) {
#pragma unroll
      for (int c = 0; c < CPG; ++c) {
        float a = b_dp[c0 + c];
#pragma unroll
        for (int dy = 0; dy < 3; ++dy)
#pragma unroll
          for (int dx = 0; dx < 3; ++dx)
            a = fmaf(w_dp[(c0 + c) * 9 + dy * 3 + dx],
                     ldp[(iy + dy) * 24 + (ix + dx)], a);
        lsrc[c * 22 * LSTR + iy * LSTR + ix] = ok ? a : 0.f;
      }
    } else {
      float sc = ok ? invZ[b * HWSZ + yy * WW + xx] : 0.f;
#pragma unroll
      for (int c = 0; c < CPG; ++c)
        lsrc[c * 22 * LSTR + iy * LSTR + ix] =
            ok ? src[((size_t)b * CC + c0 + c) * HWSZ + yy * WW + xx] * sc : 0.f;
    }
  }
  __syncthreads();

  // per-lane preloads
  int offs_r[16];
#pragma unroll
  for (int mt = 0; mt < 4; ++mt)
#pragma unroll
    for (int i = 0; i < 4; ++i)
      offs_r[mt * 4 + i] = loffs[mt * 16 + q * 4 + i];
  int tko[8];
#pragma unroll
  for (int j = 0; j < 8; ++j) tko[j] = lltk[q * 8 + j];

  // build split-bf16 B fragments (patch matrix) for this wave's 4 pixel rows
  short8 Bhi[4], Blo[4];
#pragma unroll
  for (int nt = 0; nt < 4; ++nt) {
    int py = wv * 4 + nt;
#pragma unroll
    for (int j = 0; j < 8; ++j) {
      int o = tko[j];
      float v = (o == -1) ? 1.f : ((o == -2) ? 0.f : lt[o + py * 18 + col]);
      short h = f2bf(v);
      Bhi[nt][j] = h;
      Blo[nt][j] = f2bf(v - bf2f(h));
    }
  }

  float acc[3][4];
  float zacc[4] = {0.f, 0.f, 0.f, 0.f};
#pragma unroll
  for (int c = 0; c < 3; ++c)
#pragma unroll
    for (int nt = 0; nt < 4; ++nt) acc[c][nt] = 0.f;

#pragma unroll
  for (int c = 0; c < 3; ++c) {
    const float* lsc = lsrc + c * 22 * LSTR;
#pragma unroll
    for (int mt = 0; mt < 4; ++mt) {
      const short8 Ahi =
          *(const short8*)&lw[((c * 4 + mt) * 2 + 0) * 640 + col * 40 + q * 8];
      const short8 Alo =
          *(const short8*)&lw[((c * 4 + mt) * 2 + 1) * 640 + col * 40 + q * 8];
#pragma unroll
      for (int nt = 0; nt < 4; ++nt) {
        float4v C = {0.f, 0.f, 0.f, 0.f};
        C = __builtin_amdgcn_mfma_f32_16x16x32_bf16(Ahi, Bhi[nt], C, 0, 0, 0);
        C = __builtin_amdgcn_mfma_f32_16x16x32_bf16(Ahi, Blo[nt], C, 0, 0, 0);
        C = __builtin_amdgcn_mfma_f32_16x16x32_bf16(Alo, Bhi[nt], C, 0, 0, 0);
        int base = (wv * 4 + nt + 3) * LSTR + (col + 3);
        if (mt < 3) {
#pragma unroll
          for (int i = 0; i < 4; ++i) {
            float e = __expf(C[i]);
            if (FIRST) zacc[nt] += e;
            acc[c][nt] = fmaf(e, lsc[base + offs_r[mt * 4 + i]], acc[c][nt]);
          }
        } else {
          // only tap row 48 (q==0, i==0) is real in M-tile 3
          float e = __expf(C[0]);
          e = (q == 0) ? e : 0.f;
          if (FIRST) zacc[nt] += e;
          acc[c][nt] = fmaf(e, lsc[base + offs_r[12]], acc[c][nt]);
        }
      }
    }
  }

  // cross-quad reductions + stores
#pragma unroll
  for (int nt = 0; nt < 4; ++nt) {
    int p = (y0 + wv * 4 + nt) * WW + (x0 + col);
    if (FIRST) {
      float z = zacc[nt];
      z += __shfl_xor(z, 16, 64);
      z += __shfl_xor(z, 32, 64);
      if (lane < 16) part[(size_t)g * BB * HWSZ + b * HWSZ + p] = z;
    }
    if (FINAL) {
      float r = 0.f;
#pragma unroll
      for (int c = 0; c < 3; ++c) {
        float v = acc[c][nt];
        v += __shfl_xor(v, 16, 64);
        v += __shfl_xor(v, 32, 64);
        r = fmaf(w_td[c0 + c], v, r);
      }
      if (lane < 16) part[(size_t)g * BB * HWSZ + b * HWSZ + p] = r;
    } else {
#pragma unroll
      for (int c = 0; c < 3; ++c) {
        float v = acc[c][nt];
        v += __shfl_xor(v, 16, 64);
        v += __shfl_xor(v, 32, 64);
        if (lane < 16) dst[((size_t)b * CC + c0 + c) * HWSZ + p] = v;
      }
    }
  }
}

// invZ = 1 / sum_g zpart (z is texture-only -> iteration-invariant)
__global__ __launch_bounds__(256) void k_zred(const float* __restrict__ zpart,
                                              float* __restrict__ invZ) {
  int t = blockIdx.x * 256 + threadIdx.x;
  float z = 0.f;
#pragma unroll
  for (int g = 0; g < G; ++g) z += zpart[(size_t)g * BB * HWSZ + t];
  invZ[t] = 1.f / z;
}

// out = (sum_g respart) * invZ + b_td
__global__ __launch_bounds__(256) void k_final(const float* __restrict__ respart,
                                               const float* __restrict__ invZ,
                                               const float* __restrict__ b_td,
                                               float* __restrict__ out) {
  int t = blockIdx.x * 256 + threadIdx.x;
  float r = 0.f;
#pragma unroll
  for (int g = 0; g < G; ++g) r += respart[(size_t)g * BB * HWSZ + t];
  out[t] = fmaf(r, invZ[t], b_td[0]);
}

// ---------------------------------------------------------------------------
extern "C" void kernel_launch(void* const* d_in, const int* in_sizes, int n_in,
                              void* d_out, int out_size, void* d_ws, size_t ws_size,
                              hipStream_t stream) {
  const float* depth = (const float*)d_in[0];
  const float* tex   = (const float*)d_in[1];
  const float* w_dp  = (const float*)d_in[2];
  const float* b_dp  = (const float*)d_in[3];
  const float* w_kp  = (const float*)d_in[4];
  const float* b_kp  = (const float*)d_in[5];
  const float* w_td  = (const float*)d_in[6];
  const float* b_td  = (const float*)d_in[7];
  float* out = (float*)d_out;

  // ws: bufA/bufB ping-pong (12.58 MB each) + part (4.19 MB) + invZ (0.5 MB)
  //     + wsW (0.25 MB)  => ~30.1 MB total
  char* ws = (char*)d_ws;
  const size_t buf_b = (size_t)BB * CC * HWSZ * 4;
  float* bufA = (float*)ws;
  float* bufB = (float*)(ws + buf_b);
  float* part = (float*)(ws + 2 * buf_b);
  float* invZ = (float*)(ws + 2 * buf_b + (size_t)G * BB * HWSZ * 4);
  short* wsW  = (short*)(ws + 2 * buf_b + (size_t)G * BB * HWSZ * 4 +
                         (size_t)BB * HWSZ * 4);

  k_wsetup<<<dim3(192), dim3(64), 0, stream>>>(w_kp, b_kp, wsW);

  dim3 grid(WW / 16, HH / 16, BB * G), blk(256);
  dim3 grid1(BB * HWSZ / 256), blk1(256);

  // iter1: fused depth_latent; emits unnormalized acc + partial z
  k_diffuse_m<true, false><<<grid, blk, 0, stream>>>(
      depth, nullptr, nullptr, tex, w_dp, b_dp, wsW, bufB, part, w_td);
  k_zred<<<grid1, blk1, 0, stream>>>(part, invZ);
  // iters 2,3: unnormalized ping-pong, invZ folded into staging
  k_diffuse_m<false, false><<<grid, blk, 0, stream>>>(
      depth, bufB, invZ, tex, w_dp, b_dp, wsW, bufA, part, w_td);
  k_diffuse_m<false, false><<<grid, blk, 0, stream>>>(
      depth, bufA, invZ, tex, w_dp, b_dp, wsW, bufB, part, w_td);
  // iter4: per-group to_depth partials
  k_diffuse_m<false, true><<<grid, blk, 0, stream>>>(
      depth, bufB, invZ, tex, w_dp, b_dp, wsW, nullptr, part, w_td);
  k_final<<<grid1, blk1, 0, stream>>>(part, invZ, b_td, out);
}

// Round 5
// 333.275 us; speedup vs baseline: 4.4751x; 4.4751x over previous
//
#include <hip/hip_runtime.h>

// Problem constants
#define BB   2
#define HH   256
#define WW   256
#define HWSZ (HH * WW)        // 65536
#define CC   24
#define KSZ  7
#define KK   49               // 7*7
#define PADK 3
#define G    8                // channel groups
#define CPG  3                // channels per group
#define LSTR 24               // src halo row stride (22 padded to 24)

typedef __attribute__((ext_vector_type(8))) short short8;
typedef __attribute__((ext_vector_type(4))) float float4v;

// float -> bf16 bits (round-to-nearest-even) and back
__device__ __forceinline__ short f2bf(float x) {
  unsigned u = __builtin_bit_cast(unsigned, x);
  unsigned r = u + 0x7FFFu + ((u >> 16) & 1u);
  return (short)(r >> 16);
}
__device__ __forceinline__ float bf2f(short h) {
  unsigned u = ((unsigned)(unsigned short)h) << 16;
  return __builtin_bit_cast(float, u);
}

// ---------------------------------------------------------------------------
// Setup: split-bf16 W fragments in MFMA A-operand layout (verified R3).
// wsW[blk][row 16][k 40], blk = ((g*3+c)*4 + mt)*2 + s  (192 blocks x 640)
// row = m in M-tile (tap row kk = mt*16+row), k = 0..26 conv wts, 27 bias.
// ---------------------------------------------------------------------------
__global__ __launch_bounds__(64) void k_wsetup(
    const float* __restrict__ w_kp, const float* __restrict__ b_kp,
    short* __restrict__ wsW) {
  int blk = blockIdx.x;
  int s = blk & 1, mt = (blk >> 1) & 3, cg = blk >> 3;   // cg = g*3+c
  for (int idx = threadIdx.x; idx < 640; idx += 64) {
    int row = idx / 40, k = idx % 40;
    int kk = mt * 16 + row;
    float v = 0.f;
    if (kk < KK && k < 28)
      v = (k < 27) ? w_kp[((size_t)cg * KK + kk) * 27 + k] : b_kp[cg * KK + kk];
    short hi = f2bf(v);
    short h = (s == 0) ? hi : f2bf(v - bf2f(hi));
    wsW[(size_t)blk * 640 + idx] = h;
  }
}

// ---------------------------------------------------------------------------
// One diffusion iteration, logit conv via split-bf16 MFMA (3 MFMAs ~ fp32).
// Per block: 16x16 pixel tile x 3-channel group. Flat loop idx=(c*4+mt),
// ROLLED (#pragma unroll 1) so only one A-frag pair + 4 C-tiles are live
// -> no scratch spill (R3's failure mode). A-frags read from L2-hot wsW
// with one-iteration manual prefetch; NO LDS W-stage -> 12.9 KB LDS total.
// C-layout: col=lane&15=pixel-x, row=q*4+i=tap (verified). Epilogue per C:
// e=exp(logit); z+=e (FIRST, texture-only -> computed once); acc+=e*lsrc.
// ---------------------------------------------------------------------------
template <bool FIRST, bool FINAL>
__global__ __launch_bounds__(256, 4) void k_diffuse_m(
    const float* __restrict__ depth, const float* __restrict__ src,
    const float* __restrict__ invZ, const float* __restrict__ tex,
    const float* __restrict__ w_dp, const float* __restrict__ b_dp,
    const short* __restrict__ wsW, float* __restrict__ dst,
    float* __restrict__ part, const float* __restrict__ w_td) {
  __shared__ float lsrc[CPG * 22 * LSTR];          // 6336 B
  __shared__ float lt[3 * 324];                    // 3888 B (18x18 tex halo)
  __shared__ float ldp[576];                       // 2304 B (24x24 depth halo)
  __shared__ int loffs[64];                        // tap row -> src-halo offset
  __shared__ int lltk[32];                         // k -> tex-halo offset

  int b = blockIdx.z / G, g = blockIdx.z % G, c0 = g * CPG;
  int x0 = blockIdx.x * 16, y0 = blockIdx.y * 16;
  int tid = threadIdx.x;
  int lane = tid & 63, wv = tid >> 6;
  int q = lane >> 4, col = lane & 15;

  // tables
  if (tid < 64) {
    int r = tid;
    loffs[r] = (r < KK) ? ((r / 7) - 3) * LSTR + ((r % 7) - 3) : 0;
  } else if (tid < 96) {
    int k = tid - 64, v;
    if (k < 27) v = (k / 9) * 324 + ((k % 9) / 3) * 18 + (k % 3);
    else if (k == 27) v = -1;       // bias slot: patch value 1.0
    else v = -2;                    // K padding: 0.0
    lltk[k] = v;
  }
  // stage texture halo (18x18 per channel)
  for (int idx = tid; idx < 972; idx += 256) {
    int ci = idx / 324, r = idx % 324;
    int iy = r / 18, ix = r % 18;
    int yy = y0 + iy - 1, xx = x0 + ix - 1;
    bool ok = (yy >= 0 && yy < HH && xx >= 0 && xx < WW);
    lt[idx] = ok ? tex[((size_t)b * 3 + ci) * HWSZ + yy * WW + xx] : 0.f;
  }
  if (FIRST) {
    for (int idx = tid; idx < 576; idx += 256) {   // depth halo 24x24 @(-4,-4)
      int iy = idx / 24, ix = idx % 24;
      int yy = y0 + iy - 4, xx = x0 + ix - 4;
      bool ok = (yy >= 0 && yy < HH && xx >= 0 && xx < WW);
      ldp[idx] = ok ? depth[(size_t)b * HWSZ + yy * WW + xx] : 0.f;
    }
  }
  __syncthreads();

  // stage src halo (22x22 @(-3,-3)); FIRST fuses depth_latent conv,
  // later iters fold previous 1/Z into the (unnormalized) src.
  for (int idx = tid; idx < 484; idx += 256) {
    int iy = idx / 22, ix = idx % 22;
    int yy = y0 + iy - PADK, xx = x0 + ix - PADK;
    bool ok = (yy >= 0 && yy < HH && xx >= 0 && xx < WW);
    if (FIRST) {
#pragma unroll
      for (int c = 0; c < CPG; ++c) {
        float a = b_dp[c0 + c];
#pragma unroll
        for (int dy = 0; dy < 3; ++dy)
#pragma unroll
          for (int dx = 0; dx < 3; ++dx)
            a = fmaf(w_dp[(c0 + c) * 9 + dy * 3 + dx],
                     ldp[(iy + dy) * 24 + (ix + dx)], a);
        lsrc[c * 22 * LSTR + iy * LSTR + ix] = ok ? a : 0.f;
      }
    } else {
      float sc = ok ? invZ[b * HWSZ + yy * WW + xx] : 0.f;
#pragma unroll
      for (int c = 0; c < CPG; ++c)
        lsrc[c * 22 * LSTR + iy * LSTR + ix] =
            ok ? src[((size_t)b * CC + c0 + c) * HWSZ + yy * WW + xx] * sc : 0.f;
    }
  }
  __syncthreads();

  // build split-bf16 B fragments (patch matrix), 4 pixel rows per wave
  int tko[8];
#pragma unroll
  for (int j = 0; j < 8; ++j) tko[j] = lltk[q * 8 + j];
  short8 Bhi[4], Blo[4];
#pragma unroll
  for (int nt = 0; nt < 4; ++nt) {
    int py = wv * 4 + nt;
#pragma unroll
    for (int j = 0; j < 8; ++j) {
      int o = tko[j];
      float v = (o == -1) ? 1.f : ((o == -2) ? 0.f : lt[o + py * 18 + col]);
      short h = f2bf(v);
      Bhi[nt][j] = h;
      Blo[nt][j] = f2bf(v - bf2f(h));
    }
  }

  float accc[4] = {0.f, 0.f, 0.f, 0.f};
  float zacc[4] = {0.f, 0.f, 0.f, 0.f};
  float res[4]  = {0.f, 0.f, 0.f, 0.f};

  // flat (c,mt) loop with one-iteration A-frag prefetch from global (L2-hot)
  const short* wp0 = wsW + (size_t)c0 * 5120 + col * 40 + q * 8;
  short8 nAhi = *(const short8*)(wp0);
  short8 nAlo = *(const short8*)(wp0 + 640);
#pragma unroll 1
  for (int idx = 0; idx < 12; ++idx) {
    short8 Ahi = nAhi, Alo = nAlo;
    if (idx < 11) {
      const short* wpn = wp0 + (idx + 1) * 1280;
      nAhi = *(const short8*)(wpn);
      nAlo = *(const short8*)(wpn + 640);
    }
    int c = idx >> 2, mt = idx & 3;
    const float* lsc = lsrc + c * 22 * LSTR;
    int o0 = loffs[mt * 16 + q * 4 + 0];
    int o1 = loffs[mt * 16 + q * 4 + 1];
    int o2 = loffs[mt * 16 + q * 4 + 2];
    int o3 = loffs[mt * 16 + q * 4 + 3];
#pragma unroll
    for (int nt = 0; nt < 4; ++nt) {
      float4v C = {0.f, 0.f, 0.f, 0.f};
      C = __builtin_amdgcn_mfma_f32_16x16x32_bf16(Ahi, Bhi[nt], C, 0, 0, 0);
      C = __builtin_amdgcn_mfma_f32_16x16x32_bf16(Ahi, Blo[nt], C, 0, 0, 0);
      C = __builtin_amdgcn_mfma_f32_16x16x32_bf16(Alo, Bhi[nt], C, 0, 0, 0);
      int base = (wv * 4 + nt + 3) * LSTR + (col + 3);
      if (mt < 3) {
        float e0 = __expf(C[0]), e1 = __expf(C[1]);
        float e2 = __expf(C[2]), e3 = __expf(C[3]);
        if (FIRST) zacc[nt] += (e0 + e1) + (e2 + e3);
        float a = accc[nt];
        a = fmaf(e0, lsc[base + o0], a);
        a = fmaf(e1, lsc[base + o1], a);
        a = fmaf(e2, lsc[base + o2], a);
        a = fmaf(e3, lsc[base + o3], a);
        accc[nt] = a;
      } else {
        // only tap row 48 (q==0, i==0) is real in M-tile 3
        float e = (q == 0) ? __expf(C[0]) : 0.f;
        if (FIRST) zacc[nt] += e;
        accc[nt] = fmaf(e, lsc[base + o0], accc[nt]);
      }
    }
    if (mt == 3) {
      // finish channel c: cross-quad reduce, store / accumulate
#pragma unroll
      for (int nt = 0; nt < 4; ++nt) {
        float v = accc[nt];
        v += __shfl_xor(v, 16, 64);
        v += __shfl_xor(v, 32, 64);
        if (FINAL) {
          res[nt] = fmaf(w_td[c0 + c], v, res[nt]);
        } else {
          int p = (y0 + wv * 4 + nt) * WW + (x0 + col);
          if (lane < 16) dst[((size_t)b * CC + c0 + c) * HWSZ + p] = v;
        }
        accc[nt] = 0.f;
      }
    }
  }

  // tail stores
#pragma unroll
  for (int nt = 0; nt < 4; ++nt) {
    int p = (y0 + wv * 4 + nt) * WW + (x0 + col);
    if (FIRST) {
      float z = zacc[nt];
      z += __shfl_xor(z, 16, 64);
      z += __shfl_xor(z, 32, 64);
      if (lane < 16) part[(size_t)g * BB * HWSZ + b * HWSZ + p] = z;
    }
    if (FINAL) {
      if (lane < 16) part[(size_t)g * BB * HWSZ + b * HWSZ + p] = res[nt];
    }
  }
}

// invZ = 1 / sum_g zpart (z is texture-only -> iteration-invariant)
__global__ __launch_bounds__(256) void k_zred(const float* __restrict__ zpart,
                                              float* __restrict__ invZ) {
  int t = blockIdx.x * 256 + threadIdx.x;
  float z = 0.f;
#pragma unroll
  for (int g = 0; g < G; ++g) z += zpart[(size_t)g * BB * HWSZ + t];
  invZ[t] = 1.f / z;
}

// out = (sum_g respart) * invZ + b_td
__global__ __launch_bounds__(256) void k_final(const float* __restrict__ respart,
                                               const float* __restrict__ invZ,
                                               const float* __restrict__ b_td,
                                               float* __restrict__ out) {
  int t = blockIdx.x * 256 + threadIdx.x;
  float r = 0.f;
#pragma unroll
  for (int g = 0; g < G; ++g) r += respart[(size_t)g * BB * HWSZ + t];
  out[t] = fmaf(r, invZ[t], b_td[0]);
}

// ---------------------------------------------------------------------------
extern "C" void kernel_launch(void* const* d_in, const int* in_sizes, int n_in,
                              void* d_out, int out_size, void* d_ws, size_t ws_size,
                              hipStream_t stream) {
  const float* depth = (const float*)d_in[0];
  const float* tex   = (const float*)d_in[1];
  const float* w_dp  = (const float*)d_in[2];
  const float* b_dp  = (const float*)d_in[3];
  const float* w_kp  = (const float*)d_in[4];
  const float* b_kp  = (const float*)d_in[5];
  const float* w_td  = (const float*)d_in[6];
  const float* b_td  = (const float*)d_in[7];
  float* out = (float*)d_out;

  // ws: bufA/bufB (12.58 MB each) + part (4.19 MB) + invZ (0.5 MB) + wsW (0.25)
  char* ws = (char*)d_ws;
  const size_t buf_b = (size_t)BB * CC * HWSZ * 4;
  float* bufA = (float*)ws;
  float* bufB = (float*)(ws + buf_b);
  float* part = (float*)(ws + 2 * buf_b);
  float* invZ = (float*)(ws + 2 * buf_b + (size_t)G * BB * HWSZ * 4);
  short* wsW  = (short*)(ws + 2 * buf_b + (size_t)G * BB * HWSZ * 4 +
                         (size_t)BB * HWSZ * 4);

  k_wsetup<<<dim3(192), dim3(64), 0, stream>>>(w_kp, b_kp, wsW);

  dim3 grid(WW / 16, HH / 16, BB * G), blk(256);
  dim3 grid1(BB * HWSZ / 256), blk1(256);

  // iter1: fused depth_latent; emits unnormalized acc + partial z
  k_diffuse_m<true, false><<<grid, blk, 0, stream>>>(
      depth, nullptr, nullptr, tex, w_dp, b_dp, wsW, bufB, part, w_td);
  k_zred<<<grid1, blk1, 0, stream>>>(part, invZ);
  // iters 2,3: unnormalized ping-pong, invZ folded into staging
  k_diffuse_m<false, false><<<grid, blk, 0, stream>>>(
      depth, bufB, invZ, tex, w_dp, b_dp, wsW, bufA, part, w_td);
  k_diffuse_m<false, false><<<grid, blk, 0, stream>>>(
      depth, bufA, invZ, tex, w_dp, b_dp, wsW, bufB, part, w_td);
  // iter4: per-group to_depth partials
  k_diffuse_m<false, true><<<grid, blk, 0, stream>>>(
      depth, bufB, invZ, tex, w_dp, b_dp, wsW, nullptr, part, w_td);
  k_final<<<grid1, blk1, 0, stream>>>(part, invZ, b_td, out);
}

// Round 6
// 295.560 us; speedup vs baseline: 5.0461x; 1.1276x over previous
//
#include <hip/hip_runtime.h>

// Problem constants
#define BB   2
#define HH   256
#define WW   256
#define HWSZ (HH * WW)        // 65536
#define CC   24
#define KSZ  7
#define KK   49               // 7*7
#define PADK 3
#define G    8                // channel groups
#define CPG  3                // channels per group
#define LSTR 24               // src halo row stride (22 padded to 24)
#define LOG2E 1.44269504088896340736f

typedef __attribute__((ext_vector_type(8))) short short8;
typedef __attribute__((ext_vector_type(4))) float float4v;

// float -> bf16 bits (round-to-nearest-even) and back
__device__ __forceinline__ short f2bf(float x) {
  unsigned u = __builtin_bit_cast(unsigned, x);
  unsigned r = u + 0x7FFFu + ((u >> 16) & 1u);
  return (short)(r >> 16);
}
__device__ __forceinline__ float bf2f(short h) {
  unsigned u = ((unsigned)(unsigned short)h) << 16;
  return __builtin_bit_cast(float, u);
}

// ---------------------------------------------------------------------------
// Setup: split-bf16 W fragments, PRE-SCALED by log2e so the kernel uses
// exp2 directly (exp(x) = exp2(x*log2e); softmax invariant, exact).
// wsW[blk][row 16][k 40], blk = ((g*3+c)*4 + mt)*2 + s  (192 blocks x 640)
// ---------------------------------------------------------------------------
__global__ __launch_bounds__(64) void k_wsetup(
    const float* __restrict__ w_kp, const float* __restrict__ b_kp,
    short* __restrict__ wsW) {
  int blk = blockIdx.x;
  int s = blk & 1, mt = (blk >> 1) & 3, cg = blk >> 3;   // cg = g*3+c
  for (int idx = threadIdx.x; idx < 640; idx += 64) {
    int row = idx / 40, k = idx % 40;
    int kk = mt * 16 + row;
    float v = 0.f;
    if (kk < KK && k < 28)
      v = ((k < 27) ? w_kp[((size_t)cg * KK + kk) * 27 + k]
                    : b_kp[cg * KK + kk]) * LOG2E;
    short hi = f2bf(v);
    short h = (s == 0) ? hi : f2bf(v - bf2f(hi));
    wsW[(size_t)blk * 640 + idx] = h;
  }
}

// ---------------------------------------------------------------------------
// Setup: split-bf16 B fragments (texture patch matrix) — identical for all
// 4 diffusion dispatches, so build ONCE. Layout for coalesced b128 loads:
// int4 index = (((b*256+tile)*4 + wv)*4 + nt)*2 + s) * 64 + lane.
// ---------------------------------------------------------------------------
__global__ __launch_bounds__(256) void k_bsetup(
    const float* __restrict__ tex, short* __restrict__ wsB) {
  __shared__ float lt[3 * 324];   // 18x18 tex halo
  __shared__ int lltk[32];        // k -> tex-halo offset
  int b = blockIdx.z;
  int x0 = blockIdx.x * 16, y0 = blockIdx.y * 16;
  int tile = blockIdx.y * 16 + blockIdx.x;
  int tid = threadIdx.x, lane = tid & 63, wv = tid >> 6;
  int q = lane >> 4, col = lane & 15;

  if (tid < 32) {
    int k = tid, v;
    if (k < 27) v = (k / 9) * 324 + ((k % 9) / 3) * 18 + (k % 3);
    else if (k == 27) v = -1;     // bias slot: patch value 1.0
    else v = -2;                  // K padding: 0.0
    lltk[k] = v;
  }
  for (int idx = tid; idx < 972; idx += 256) {
    int ci = idx / 324, r = idx % 324;
    int iy = r / 18, ix = r % 18;
    int yy = y0 + iy - 1, xx = x0 + ix - 1;
    bool ok = (yy >= 0 && yy < HH && xx >= 0 && xx < WW);
    lt[idx] = ok ? tex[((size_t)b * 3 + ci) * HWSZ + yy * WW + xx] : 0.f;
  }
  __syncthreads();

  int tko[8];
#pragma unroll
  for (int j = 0; j < 8; ++j) tko[j] = lltk[q * 8 + j];
  int4* w4 = (int4*)wsB;
#pragma unroll
  for (int nt = 0; nt < 4; ++nt) {
    short8 hi, lo;
#pragma unroll
    for (int j = 0; j < 8; ++j) {
      int o = tko[j];
      float v = (o == -1) ? 1.f
                          : ((o == -2) ? 0.f : lt[o + (wv * 4 + nt) * 18 + col]);
      short h = f2bf(v);
      hi[j] = h;
      lo[j] = f2bf(v - bf2f(h));
    }
    size_t base = ((((size_t)(b * 256 + tile) * 4 + wv) * 4 + nt) * 2);
    w4[(base + 0) * 64 + lane] = __builtin_bit_cast(int4, hi);
    w4[(base + 1) * 64 + lane] = __builtin_bit_cast(int4, lo);
  }
}

// ---------------------------------------------------------------------------
// One diffusion iteration, split-bf16 MFMA logit conv, exp2 epilogue.
// Two passes (np) of 2 pixel-rows each: halves live B/C registers so
// __launch_bounds__(256,6) can hold ~6 waves/SIMD (R5 occupancy fix).
// Flat rolled (c,mt) loop w/ linear-pointer A prefetch (no-spill, per R4).
// Tap LDS reads use pointer+immediate offsets (t*LSTR compile-time).
// ---------------------------------------------------------------------------
template <bool FIRST, bool FINAL>
__global__ __launch_bounds__(256, 6) void k_diffuse_m(
    const float* __restrict__ depth, const float* __restrict__ src,
    const float* __restrict__ invZ, const float* __restrict__ w_dp,
    const float* __restrict__ b_dp, const short* __restrict__ wsW,
    const short* __restrict__ wsB, float* __restrict__ dst,
    float* __restrict__ part, const float* __restrict__ w_td) {
  __shared__ float lsrc[CPG * 22 * LSTR];          // 6336 B
  __shared__ float ldp[576];                       // 2304 B (FIRST only)
  __shared__ int loffs[64];                        // tap row -> halo offset

  int b = blockIdx.z / G, g = blockIdx.z % G, c0 = g * CPG;
  int x0 = blockIdx.x * 16, y0 = blockIdx.y * 16;
  int tile = blockIdx.y * 16 + blockIdx.x;
  int tid = threadIdx.x, lane = tid & 63, wv = tid >> 6;
  int q = lane >> 4, col = lane & 15;

  if (tid < 64)
    loffs[tid] = (tid < KK) ? ((tid / 7) - 3) * LSTR + ((tid % 7) - 3) : 0;
  if (FIRST) {
    for (int idx = tid; idx < 576; idx += 256) {   // depth halo 24x24 @(-4,-4)
      int iy = idx / 24, ix = idx % 24;
      int yy = y0 + iy - 4, xx = x0 + ix - 4;
      bool ok = (yy >= 0 && yy < HH && xx >= 0 && xx < WW);
      ldp[idx] = ok ? depth[(size_t)b * HWSZ + yy * WW + xx] : 0.f;
    }
  }
  __syncthreads();

  // stage src halo (22x22 @(-3,-3)); FIRST fuses depth_latent conv,
  // later iters fold previous 1/Z into the (unnormalized) src.
  for (int idx = tid; idx < 484; idx += 256) {
    int iy = idx / 22, ix = idx % 22;
    int yy = y0 + iy - PADK, xx = x0 + ix - PADK;
    bool ok = (yy >= 0 && yy < HH && xx >= 0 && xx < WW);
    if (FIRST) {
#pragma unroll
      for (int c = 0; c < CPG; ++c) {
        float a = b_dp[c0 + c];
#pragma unroll
        for (int dy = 0; dy < 3; ++dy)
#pragma unroll
          for (int dx = 0; dx < 3; ++dx)
            a = fmaf(w_dp[(c0 + c) * 9 + dy * 3 + dx],
                     ldp[(iy + dy) * 24 + (ix + dx)], a);
        lsrc[c * 22 * LSTR + iy * LSTR + ix] = ok ? a : 0.f;
      }
    } else {
      float sc = ok ? invZ[b * HWSZ + yy * WW + xx] : 0.f;
#pragma unroll
      for (int c = 0; c < CPG; ++c)
        lsrc[c * 22 * LSTR + iy * LSTR + ix] =
            ok ? src[((size_t)b * CC + c0 + c) * HWSZ + yy * WW + xx] * sc : 0.f;
    }
  }
  __syncthreads();

  const int4* wB = (const int4*)wsB + ((size_t)(b * 256 + tile) * 4 + wv) * 512;

#pragma unroll 1
  for (int np = 0; np < 2; ++np) {
    // B fragments for this pass's 2 pixel rows (precomputed, coalesced b128)
    short8 Bh[2], Bl[2];
#pragma unroll
    for (int t = 0; t < 2; ++t) {
      int nt = np * 2 + t;
      Bh[t] = __builtin_bit_cast(short8, wB[(nt * 2 + 0) * 64 + lane]);
      Bl[t] = __builtin_bit_cast(short8, wB[(nt * 2 + 1) * 64 + lane]);
    }
    int basep = (wv * 4 + np * 2 + 3) * LSTR + col + 3;  // row of nt2=0 pixel
    float zacc[2] = {0.f, 0.f}, res[2] = {0.f, 0.f};
    float accc[2] = {0.f, 0.f};

    const short* wp = wsW + (size_t)g * 15360 + col * 40 + q * 8;
    short8 nAh = *(const short8*)wp;
    short8 nAl = *(const short8*)(wp + 640);
#pragma unroll 1
    for (int idx = 0; idx < 12; ++idx) {
      short8 Ah = nAh, Al = nAl;
      if (idx < 11) {
        wp += 1280;
        nAh = *(const short8*)wp;
        nAl = *(const short8*)(wp + 640);
      }
      int c = idx >> 2, mt = idx & 3;
      // tap pointers (nt2 handled via compile-time imm t*LSTR)
      int cb = basep + c * 2112;
      const float* p0 = lsrc + cb + loffs[mt * 16 + q * 4 + 0];
      const float* p1 = lsrc + cb + loffs[mt * 16 + q * 4 + 1];
      const float* p2 = lsrc + cb + loffs[mt * 16 + q * 4 + 2];
      const float* p3 = lsrc + cb + loffs[mt * 16 + q * 4 + 3];
#pragma unroll
      for (int t = 0; t < 2; ++t) {
        float4v C = {0.f, 0.f, 0.f, 0.f};
        C = __builtin_amdgcn_mfma_f32_16x16x32_bf16(Ah, Bh[t], C, 0, 0, 0);
        C = __builtin_amdgcn_mfma_f32_16x16x32_bf16(Ah, Bl[t], C, 0, 0, 0);
        C = __builtin_amdgcn_mfma_f32_16x16x32_bf16(Al, Bh[t], C, 0, 0, 0);
        if (mt < 3) {
          float e0 = __builtin_amdgcn_exp2f(C[0]);
          float e1 = __builtin_amdgcn_exp2f(C[1]);
          float e2 = __builtin_amdgcn_exp2f(C[2]);
          float e3 = __builtin_amdgcn_exp2f(C[3]);
          if (FIRST) zacc[t] += (e0 + e1) + (e2 + e3);
          float a = accc[t];
          a = fmaf(e0, p0[t * LSTR], a);
          a = fmaf(e1, p1[t * LSTR], a);
          a = fmaf(e2, p2[t * LSTR], a);
          a = fmaf(e3, p3[t * LSTR], a);
          accc[t] = a;
        } else {
          // only tap row 48 (q==0, reg 0) is real in M-tile 3
          float e = (q == 0) ? __builtin_amdgcn_exp2f(C[0]) : 0.f;
          if (FIRST) zacc[t] += e;
          accc[t] = fmaf(e, p0[t * LSTR], accc[t]);
        }
      }
      if (mt == 3) {
        // channel c complete for this pass: reduce across quads, emit
#pragma unroll
        for (int t = 0; t < 2; ++t) {
          float v = accc[t];
          v += __shfl_xor(v, 16, 64);
          v += __shfl_xor(v, 32, 64);
          if (FINAL) {
            res[t] = fmaf(w_td[c0 + c], v, res[t]);
          } else {
            int p = (y0 + wv * 4 + np * 2 + t) * WW + (x0 + col);
            if (lane < 16) dst[((size_t)b * CC + c0 + c) * HWSZ + p] = v;
          }
          accc[t] = 0.f;
        }
      }
    }
    // pass tail: z (FIRST) / to_depth partials (FINAL)
#pragma unroll
    for (int t = 0; t < 2; ++t) {
      int p = (y0 + wv * 4 + np * 2 + t) * WW + (x0 + col);
      if (FIRST) {
        float z = zacc[t];
        z += __shfl_xor(z, 16, 64);
        z += __shfl_xor(z, 32, 64);
        if (lane < 16) part[(size_t)g * BB * HWSZ + b * HWSZ + p] = z;
      }
      if (FINAL) {
        if (lane < 16) part[(size_t)g * BB * HWSZ + b * HWSZ + p] = res[t];
      }
    }
  }
}

// invZ = 1 / sum_g zpart (z is texture-only -> iteration-invariant)
__global__ __launch_bounds__(256) void k_zred(const float* __restrict__ zpart,
                                              float* __restrict__ invZ) {
  int t = blockIdx.x * 256 + threadIdx.x;
  float z = 0.f;
#pragma unroll
  for (int g = 0; g < G; ++g) z += zpart[(size_t)g * BB * HWSZ + t];
  invZ[t] = 1.f / z;
}

// out = (sum_g respart) * invZ + b_td
__global__ __launch_bounds__(256) void k_final(const float* __restrict__ respart,
                                               const float* __restrict__ invZ,
                                               const float* __restrict__ b_td,
                                               float* __restrict__ out) {
  int t = blockIdx.x * 256 + threadIdx.x;
  float r = 0.f;
#pragma unroll
  for (int g = 0; g < G; ++g) r += respart[(size_t)g * BB * HWSZ + t];
  out[t] = fmaf(r, invZ[t], b_td[0]);
}

// ---------------------------------------------------------------------------
extern "C" void kernel_launch(void* const* d_in, const int* in_sizes, int n_in,
                              void* d_out, int out_size, void* d_ws, size_t ws_size,
                              hipStream_t stream) {
  const float* depth = (const float*)d_in[0];
  const float* tex   = (const float*)d_in[1];
  const float* w_dp  = (const float*)d_in[2];
  const float* b_dp  = (const float*)d_in[3];
  const float* w_kp  = (const float*)d_in[4];
  const float* b_kp  = (const float*)d_in[5];
  const float* w_td  = (const float*)d_in[6];
  const float* b_td  = (const float*)d_in[7];
  float* out = (float*)d_out;

  // ws: bufA/bufB (12.58 MB ea) + part (4.19 MB) + invZ (0.5 MB)
  //     + wsW (0.25 MB) + wsB (16.78 MB)  => ~47 MB
  char* ws = (char*)d_ws;
  const size_t buf_b = (size_t)BB * CC * HWSZ * 4;
  float* bufA = (float*)ws;
  float* bufB = (float*)(ws + buf_b);
  float* part = (float*)(ws + 2 * buf_b);
  float* invZ = (float*)(ws + 2 * buf_b + (size_t)G * BB * HWSZ * 4);
  short* wsW  = (short*)(ws + 2 * buf_b + (size_t)G * BB * HWSZ * 4 +
                         (size_t)BB * HWSZ * 4);
  short* wsB  = (short*)(ws + 2 * buf_b + (size_t)G * BB * HWSZ * 4 +
                         (size_t)BB * HWSZ * 4 + 192 * 640 * 2);

  k_wsetup<<<dim3(192), dim3(64), 0, stream>>>(w_kp, b_kp, wsW);
  k_bsetup<<<dim3(16, 16, BB), dim3(256), 0, stream>>>(tex, wsB);

  dim3 grid(WW / 16, HH / 16, BB * G), blk(256);
  dim3 grid1(BB * HWSZ / 256), blk1(256);

  // iter1: fused depth_latent; emits unnormalized acc + partial z
  k_diffuse_m<true, false><<<grid, blk, 0, stream>>>(
      depth, nullptr, nullptr, w_dp, b_dp, wsW, wsB, bufB, part, w_td);
  k_zred<<<grid1, blk1, 0, stream>>>(part, invZ);
  // iters 2,3: unnormalized ping-pong, invZ folded into staging
  k_diffuse_m<false, false><<<grid, blk, 0, stream>>>(
      depth, bufB, invZ, w_dp, b_dp, wsW, wsB, bufA, part, w_td);
  k_diffuse_m<false, false><<<grid, blk, 0, stream>>>(
      depth, bufA, invZ, w_dp, b_dp, wsW, wsB, bufB, part, w_td);
  // iter4: per-group to_depth partials
  k_diffuse_m<false, true><<<grid, blk, 0, stream>>>(
      depth, bufB, invZ, w_dp, b_dp, wsW, wsB, nullptr, part, w_td);
  k_final<<<grid1, blk1, 0, stream>>>(part, invZ, b_td, out);
}